// Round 7
// baseline (4173.162 us; speedup 1.0000x reference)
//
#include <hip/hip_runtime.h>
#include <stdint.h>

#define N_ROWS 32768
#define DIM    512
#define NQ     4
#define NCODES 2048
#define BETA   0.25
#define EPS_RESCUE 0.02f   // MFMA-score gap below which we np-mimic rescore ALL codes

typedef __attribute__((ext_vector_type(8))) short bf16x8;
typedef __attribute__((ext_vector_type(4))) float f32x4;

// ---- ws layout (bytes) ----
#define WS_LOSS   0          // 512 doubles (4 KB)
#define WS_CN     4096       // Q*K floats (32 KB)
#define WS_GAP    36864      // N floats (128 KB)
#define WS_PART   167936     // 16 * N float4 (8 MB)
#define WS_CBH    8556544    // Q*K*D ushort (8 MB)
#define WS_CBL    16945152   // Q*K*D ushort (8 MB)
#define WS_RESH   25333760   // N*D ushort (32 MB) residual hi
#define WS_RESL   58888192   // N*D ushort (32 MB) residual lo

__device__ __forceinline__ ushort f2bf(float f) {
  union { float f; uint32_t u; } v; v.f = f;
  uint32_t r = v.u + 0x7fffu + ((v.u >> 16) & 1u);
  return (ushort)(r >> 16);
}
__device__ __forceinline__ float bf2f(ushort h) {
  union { uint32_t u; float f; } v; v.u = ((uint32_t)h) << 16; return v.f;
}

// ---- numpy pairwise sum (blocksize 128, 8-way unrolled) of squares of 512 floats ----
__device__ __forceinline__ float np_pairwise_sq512(const float* buf, int lane) {
  const int blk = lane >> 3, j = lane & 7;
  const float* p = buf + ((lane < 32) ? (blk * 128 + j) : 0);
  float a = p[0];
  float acc = __fmul_rn(a, a);
#pragma unroll
  for (int i = 1; i < 16; ++i) {
    a = p[i * 8];
    acc = __fadd_rn(acc, __fmul_rn(a, a));
  }
  float s[4];
#pragma unroll
  for (int b = 0; b < 4; ++b) {
    const float p0 = __shfl(acc, b * 8 + 0), p1 = __shfl(acc, b * 8 + 1);
    const float p2 = __shfl(acc, b * 8 + 2), p3 = __shfl(acc, b * 8 + 3);
    const float p4 = __shfl(acc, b * 8 + 4), p5 = __shfl(acc, b * 8 + 5);
    const float p6 = __shfl(acc, b * 8 + 6), p7 = __shfl(acc, b * 8 + 7);
    s[b] = __fadd_rn(__fadd_rn(__fadd_rn(p0, p1), __fadd_rn(p2, p3)),
                     __fadd_rn(__fadd_rn(p4, p5), __fadd_rn(p6, p7)));
  }
  return __fadd_rn(__fadd_rn(s[0], s[1]), __fadd_rn(s[2], s[3]));
}

__global__ __launch_bounds__(64)
void cnorm_kernel(const float* __restrict__ cb, float* __restrict__ Cn) {
  const int row = blockIdx.x, lane = threadIdx.x;
  __shared__ float buf[DIM];
  const float* p = cb + (size_t)row * DIM + lane * 8;
  float4 a = *(const float4*)p, b = *(const float4*)(p + 4);
  *(float4*)&buf[lane * 8]     = a;
  *(float4*)&buf[lane * 8 + 4] = b;
  __syncthreads();
  const float v = np_pairwise_sq512(buf, lane);
  if (lane == 0) Cn[row] = v;
}

// ---- split fp32 array into bf16 hi/lo (used for codebooks AND for x at stage 0) ----
__global__ __launch_bounds__(256)
void cbsplit_kernel(const float* __restrict__ cb, ushort* __restrict__ hi, ushort* __restrict__ lo) {
  const size_t i = ((size_t)blockIdx.x * 256 + threadIdx.x) * 8;
  float4 a = *(const float4*)(cb + i), b = *(const float4*)(cb + i + 4);
  const float f[8] = {a.x, a.y, a.z, a.w, b.x, b.y, b.z, b.w};
  ushort h[8], l[8];
#pragma unroll
  for (int j = 0; j < 8; ++j) {
    h[j] = f2bf(f[j]);
    l[j] = f2bf(f[j] - bf2f(h[j]));
  }
  *(ushort4*)(hi + i)     = make_ushort4(h[0], h[1], h[2], h[3]);
  *(ushort4*)(hi + i + 4) = make_ushort4(h[4], h[5], h[6], h[7]);
  *(ushort4*)(lo + i)     = make_ushort4(l[0], l[1], l[2], l[3]);
  *(ushort4*)(lo + i + 4) = make_ushort4(l[4], l[5], l[6], l[7]);
}

__device__ __forceinline__ void top2_insert(float s, int c, float& v1, int& i1, float& v2, int& i2) {
  if (s > v1 || (s == v1 && c < i1)) { v2 = v1; i2 = i1; v1 = s; i1 = c; }
  else if (s > v2 || (s == v2 && c < i2)) { v2 = s; i2 = c; }
}

// ---------------- MFMA bf16x3 score + per-(rowtile,codetile) top-2 ----------------
// v8: NO LDS staging at all — fragments load directly global->register.
// Rationale: block-level operand reuse here is only 2x (two waves share each
// operand half; the x4 fragment reuse is already in registers), so LDS bought a
// 2x L2-traffic saving at the cost of ~24MB/CU LDS traffic (co-critical with
// MFMA), 2 barriers per kc, and vmcnt drains. Direct loads: no barriers in the
// main loop, waves fully independent, compiler pipelines kc+1 loads under kc
// MFMAs, L1 serves the twin wave's re-reads. R2 swizzle was self-inverse, so the
// staged fragment equals resh[row*512+k0+lq*8] — the direct load reads the same
// address: bit-identical fragments, same MFMA term order -> identical outputs.
__global__ __launch_bounds__(256)
void argmax_kernel(const ushort* __restrict__ resh, const ushort* __restrict__ resl,
                   const ushort* __restrict__ cbh, const ushort* __restrict__ cbl,
                   const float* __restrict__ Cn, float4* __restrict__ partials)
{
  __shared__ float4 mbuf[4][64];

  const int t    = threadIdx.x;
  const int lane = t & 63, w = t >> 6;
  const int ct = blockIdx.x & 15, rt = blockIdx.x >> 4;   // consecutive blocks share rt
  const int m0 = rt * 128, c0 = ct * 128;
  const int lm = lane & 15, lq = lane >> 4;
  const int wr = w >> 1, wc = w & 1;   // wave tile: rows [wr*64,+64), codes [wc*64,+64)

  // per-lane fragment base offsets (in ushorts); k advances by kc*32 + lq*8
  const size_t abase = (size_t)(m0 + wr * 64 + lm) * DIM + lq * 8;
  const size_t bbase = (size_t)(c0 + wc * 64 + lm) * DIM + lq * 8;

  f32x4 acc[4][4];   // [nt codes][mt rows]
#pragma unroll
  for (int nt = 0; nt < 4; ++nt)
#pragma unroll
    for (int mt = 0; mt < 4; ++mt) acc[nt][mt] = (f32x4){0.f, 0.f, 0.f, 0.f};

#pragma unroll 2
  for (int kc = 0; kc < 16; ++kc) {
    const int k0 = kc * 32;
    bf16x8 ch[4], cl[4], rh[4], rl[4];
#pragma unroll
    for (int nt = 0; nt < 4; ++nt) {
      const size_t g = bbase + (size_t)(nt * 16) * DIM + k0;
      ch[nt] = *(const bf16x8*)(cbh + g);
      cl[nt] = *(const bf16x8*)(cbl + g);
    }
#pragma unroll
    for (int mt = 0; mt < 4; ++mt) {
      const size_t g = abase + (size_t)(mt * 16) * DIM + k0;
      rh[mt] = *(const bf16x8*)(resh + g);
      rl[mt] = *(const bf16x8*)(resl + g);
    }
    // swapped operands: D[code][row]; per-acc term order ch*rh, cl*rh, ch*rl (validated)
#pragma unroll
    for (int mt = 0; mt < 4; ++mt)
#pragma unroll
      for (int nt = 0; nt < 4; ++nt) {
        acc[nt][mt] = __builtin_amdgcn_mfma_f32_16x16x32_bf16(ch[nt], rh[mt], acc[nt][mt], 0, 0, 0);
        acc[nt][mt] = __builtin_amdgcn_mfma_f32_16x16x32_bf16(cl[nt], rh[mt], acc[nt][mt], 0, 0, 0);
        acc[nt][mt] = __builtin_amdgcn_mfma_f32_16x16x32_bf16(ch[nt], rl[mt], acc[nt][mt], 0, 0, 0);
      }
  }

  // ---- epilogue: score = G - 0.5*||c||^2; codes in-lane (nt,r) + across lq ----
  float hc[4][4];
#pragma unroll
  for (int nt = 0; nt < 4; ++nt)
#pragma unroll
    for (int r = 0; r < 4; ++r)
      hc[nt][r] = 0.5f * Cn[c0 + wc * 64 + nt * 16 + lq * 4 + r];

#pragma unroll
  for (int mt = 0; mt < 4; ++mt) {   // wave-local row = mt*16 + lm
    float v1 = -3.4e38f, v2 = -3.4e38f;
    int   i1 = 0x7fffffff, i2 = 0x7fffffff;
#pragma unroll
    for (int nt = 0; nt < 4; ++nt)
#pragma unroll
      for (int r = 0; r < 4; ++r)
        top2_insert(acc[nt][mt][r] - hc[nt][r],
                    c0 + wc * 64 + nt * 16 + lq * 4 + r, v1, i1, v2, i2);
#pragma unroll
    for (int off = 16; off <= 32; off <<= 1) {   // merge lanes lm, lm+16, lm+32, lm+48
      const float ov1 = __shfl_xor(v1, off); const int oi1 = __shfl_xor(i1, off);
      const float ov2 = __shfl_xor(v2, off); const int oi2 = __shfl_xor(i2, off);
      top2_insert(ov1, oi1, v1, i1, v2, i2);
      top2_insert(ov2, oi2, v1, i1, v2, i2);
    }
    if (lq == 0) mbuf[w][mt * 16 + lm] = make_float4(v1, (float)i1, v2, (float)i2);
  }
  __syncthreads();
  if (t < 128) {   // row t: merge the 2 waves covering this row half
    const int half = t >> 6, rr = t & 63;
    float v1 = -3.4e38f, v2 = -3.4e38f;
    int   i1 = 0x7fffffff, i2 = 0x7fffffff;
#pragma unroll
    for (int ww = 0; ww < 2; ++ww) {
      float4 p = mbuf[half * 2 + ww][rr];
      top2_insert(p.x, (int)p.y, v1, i1, v2, i2);
      top2_insert(p.z, (int)p.w, v1, i1, v2, i2);
    }
    partials[(size_t)ct * N_ROWS + m0 + t] = make_float4(v1, (float)i1, v2, (float)i2);
  }
}

// ---- merge 16 code-tile partials per row -> idx + gap ----
__global__ __launch_bounds__(256)
void mergetop_kernel(const float4* __restrict__ partials, float* __restrict__ idx_out,
                     float* __restrict__ gap, int stage)
{
  const int row = blockIdx.x * 256 + threadIdx.x;
  float v1 = -3.4e38f, v2 = -3.4e38f;
  int   i1 = 0x7fffffff, i2 = 0x7fffffff;
#pragma unroll
  for (int ctt = 0; ctt < 16; ++ctt) {
    float4 p = partials[(size_t)ctt * N_ROWS + row];
    top2_insert(p.x, (int)p.y, v1, i1, v2, i2);
    top2_insert(p.z, (int)p.w, v1, i1, v2, i2);
  }
  idx_out[(size_t)row * NQ + stage] = (float)i1;
  gap[row] = v1 - v2;
}

// ---------------- np-fp32-mimic rescue (validated) ----------------
#define RESCUE_UNROLL 4

__global__ __launch_bounds__(256)
void rescue_kernel(const float* __restrict__ x, const float* __restrict__ cb,
                   const float* __restrict__ Cn, float* __restrict__ idxf,
                   const float* __restrict__ gap, int stage)
{
  const int row = blockIdx.x;
  if (gap[row] >= EPS_RESCUE) return;
  const int t = threadIdx.x;
  const int lane = t & 63, w = t >> 6;
  __shared__ float rs[DIM];
  __shared__ float sd[4];
  __shared__ int   si[4];

  // every wave computes the identical residual f[8] (deterministic replay)
  float f[8];
  {
    const float* xp = x + (size_t)row * DIM + lane * 8;
    float4 a = *(const float4*)xp, b = *(const float4*)(xp + 4);
    f[0]=a.x; f[1]=a.y; f[2]=a.z; f[3]=a.w; f[4]=b.x; f[5]=b.y; f[6]=b.z; f[7]=b.w;
  }
  for (int p = 0; p < stage; ++p) {
    const int ip = (int)idxf[(size_t)row * NQ + p];
    const float* cp = cb + ((size_t)p * NCODES + ip) * DIM + lane * 8;
    float4 a = *(const float4*)cp, b = *(const float4*)(cp + 4);
    const float q[8] = {a.x, a.y, a.z, a.w, b.x, b.y, b.z, b.w};
#pragma unroll
    for (int k = 0; k < 8; ++k) {
      const float tt = __fsub_rn(q[k], f[k]);   // sg(xq - r)
      const float xr = __fadd_rn(f[k], tt);     // x_res (STE)
      f[k] = __fsub_rn(f[k], xr);               // next residual
    }
  }
  if (w == 0) {
#pragma unroll
    for (int k = 0; k < 8; ++k) rs[lane * 8 + k] = f[k];
  }
  __syncthreads();
  const float Rn = np_pairwise_sq512(rs, lane);

  const float* cbs = cb + (size_t)stage * NCODES * DIM;
  const float* Cns = Cn + stage * NCODES;
  float dbest = 3.4e38f;
  int   ibest = 0x7fffffff;
  const int cbeg = w * (NCODES / 4);
  for (int cc = cbeg; cc < cbeg + NCODES / 4; cc += RESCUE_UNROLL) {
    float4 a[RESCUE_UNROLL], b[RESCUE_UNROLL];
#pragma unroll
    for (int u = 0; u < RESCUE_UNROLL; ++u) {
      const float* cp = cbs + (size_t)(cc + u) * DIM + lane * 8;
      a[u] = *(const float4*)cp;
      b[u] = *(const float4*)(cp + 4);
    }
    double s[RESCUE_UNROLL];
#pragma unroll
    for (int u = 0; u < RESCUE_UNROLL; ++u) {
      s[u] = (double)f[0] * a[u].x + (double)f[1] * a[u].y + (double)f[2] * a[u].z + (double)f[3] * a[u].w
           + (double)f[4] * b[u].x + (double)f[5] * b[u].y + (double)f[6] * b[u].z + (double)f[7] * b[u].w;
    }
#pragma unroll
    for (int off = 32; off; off >>= 1) {
#pragma unroll
      for (int u = 0; u < RESCUE_UNROLL; ++u) s[u] += __shfl_xor(s[u], off);
    }
#pragma unroll
    for (int u = 0; u < RESCUE_UNROLL; ++u) {
      const float G = (float)s[u];
      const float d = __fsub_rn(__fadd_rn(Rn, Cns[cc + u]), __fmul_rn(2.0f, G));
      if (d < dbest || (d == dbest && (cc + u) < ibest)) { dbest = d; ibest = cc + u; }
    }
  }
  if (lane == 0) { sd[w] = dbest; si[w] = ibest; }
  __syncthreads();
  if (t == 0) {
    float db = sd[0]; int ib = si[0];
#pragma unroll
    for (int ww = 1; ww < 4; ++ww) {
      if (sd[ww] < db || (sd[ww] == db && si[ww] < ib)) { db = sd[ww]; ib = si[ww]; }
    }
    idxf[(size_t)row * NQ + stage] = (float)ib;
  }
}

// ---------------- gather chosen code, accumulate x_q, loss, next-stage residual ----------------
__global__ __launch_bounds__(128)
void update_kernel(const float* __restrict__ x, float* __restrict__ xq_acc,
                   const float* __restrict__ cb, const float* __restrict__ idxf,
                   double* __restrict__ loss_arr,
                   ushort* __restrict__ resh, ushort* __restrict__ resl, int stage)
{
  const int n = blockIdx.x;
  const int t = threadIdx.x;
  const int idx = (int)idxf[(size_t)n * NQ + stage];
  const size_t g = (size_t)n * DIM + t * 4;

  float4 cv = *(const float4*)(cb + (size_t)idx * DIM + t * 4);
  float4 av;
  if (stage) av = *(const float4*)(xq_acc + g);
  else { av.x = 0.f; av.y = 0.f; av.z = 0.f; av.w = 0.f; }
  av.x += cv.x; av.y += cv.y; av.z += cv.z; av.w += cv.w;
  *(float4*)(xq_acc + g) = av;

  float4 xv = *(const float4*)(x + g);
  const float rx = xv.x - av.x, ry = xv.y - av.y, rz = xv.z - av.z, rw = xv.w - av.w;

  // next-stage residual bf16 hi/lo split (identical formula to cbsplit on x - xq_acc)
  {
    ushort4 h, l;
    h.x = f2bf(rx); l.x = f2bf(rx - bf2f(h.x));
    h.y = f2bf(ry); l.y = f2bf(ry - bf2f(h.y));
    h.z = f2bf(rz); l.z = f2bf(rz - bf2f(h.z));
    h.w = f2bf(rw); l.w = f2bf(rw - bf2f(h.w));
    *(ushort4*)(resh + g) = h;
    *(ushort4*)(resl + g) = l;
  }

  float s = rx * rx + ry * ry + rz * rz + rw * rw;
#pragma unroll
  for (int off = 32; off; off >>= 1) s += __shfl_down(s, off);
  __shared__ float wsum[2];
  if ((t & 63) == 0) wsum[t >> 6] = s;
  __syncthreads();
  if (t == 0) atomicAdd(&loss_arr[n & 511], (double)(wsum[0] + wsum[1]));  // 512-way fan-out
}

__global__ __launch_bounds__(64)
void finalize_kernel(const double* __restrict__ loss_arr, float* __restrict__ out_loss) {
  double s = 0.0;
  for (int i = threadIdx.x; i < 512; i += 64) s += loss_arr[i];
#pragma unroll
  for (int off = 32; off; off >>= 1) s += __shfl_down(s, off);
  if (threadIdx.x == 0)
    *out_loss = (float)(((1.0 + BETA) / ((double)NQ * (double)N_ROWS * (double)DIM)) * s);
}

extern "C" void kernel_launch(void* const* d_in, const int* in_sizes, int n_in,
                              void* d_out, int out_size, void* d_ws, size_t ws_size,
                              hipStream_t stream) {
  const float* x  = (const float*)d_in[0];
  const float* cb = (const float*)d_in[1];

  float* out_xq   = (float*)d_out;                       // [N, D]
  float* out_loss = out_xq + (size_t)N_ROWS * DIM;       // scalar
  float* out_idx  = out_loss + 1;                        // [N, Q] as float

  char* ws = (char*)d_ws;
  double* loss_arr = (double*)(ws + WS_LOSS);
  float*  Cn       = (float*) (ws + WS_CN);
  float*  gap      = (float*) (ws + WS_GAP);
  float4* partials = (float4*)(ws + WS_PART);
  ushort* cb_hi    = (ushort*)(ws + WS_CBH);
  ushort* cb_lo    = (ushort*)(ws + WS_CBL);
  ushort* res_hi   = (ushort*)(ws + WS_RESH);
  ushort* res_lo   = (ushort*)(ws + WS_RESL);

  hipMemsetAsync(ws + WS_LOSS, 0, 4096, stream);
  cbsplit_kernel<<<(NQ * NCODES * DIM) / 2048, 256, 0, stream>>>(cb, cb_hi, cb_lo);
  cbsplit_kernel<<<((size_t)N_ROWS * DIM) / 2048, 256, 0, stream>>>(x, res_hi, res_lo);  // stage-0 residual = x
  cnorm_kernel<<<NQ * NCODES, 64, 0, stream>>>(cb, Cn);

  for (int q = 0; q < NQ; ++q) {
    const float* cbq = cb + (size_t)q * NCODES * DIM;
    argmax_kernel<<<256 * 16, 256, 0, stream>>>(res_hi, res_lo,
                                                cb_hi + (size_t)q * NCODES * DIM,
                                                cb_lo + (size_t)q * NCODES * DIM,
                                                Cn + q * NCODES, partials);
    mergetop_kernel<<<N_ROWS / 256, 256, 0, stream>>>(partials, out_idx, gap, q);
    rescue_kernel<<<N_ROWS, 256, 0, stream>>>(x, cb, Cn, out_idx, gap, q);
    update_kernel<<<N_ROWS, 128, 0, stream>>>(x, out_xq, cbq, out_idx, loss_arr, res_hi, res_lo, q);
  }
  finalize_kernel<<<1, 64, 0, stream>>>(loss_arr, out_loss);
}

// Round 8
// 3023.378 us; speedup vs baseline: 1.3803x; 1.3803x over previous
//
#include <hip/hip_runtime.h>
#include <stdint.h>

#define N_ROWS 32768
#define DIM    512
#define NQ     4
#define NCODES 2048
#define BETA   0.25
#define EPS_RESCUE 0.02f   // MFMA-score gap below which we np-mimic rescore ALL codes

typedef __attribute__((ext_vector_type(8))) short bf16x8;
typedef __attribute__((ext_vector_type(4))) float f32x4;

// ---- ws layout (bytes) ----
#define WS_LOSS   0          // 512 doubles (4 KB)
#define WS_CN     4096       // Q*K floats (32 KB)
#define WS_GAP    36864      // N floats (128 KB)
#define WS_PART   167936     // 16 * N float4 (8 MB)
#define WS_CBH    8556544    // Q*K*D ushort (8 MB)
#define WS_CBL    16945152   // Q*K*D ushort (8 MB)
#define WS_RESH   25333760   // N*D ushort (32 MB) residual hi
#define WS_RESL   58888192   // N*D ushort (32 MB) residual lo

__device__ __forceinline__ ushort f2bf(float f) {
  union { float f; uint32_t u; } v; v.f = f;
  uint32_t r = v.u + 0x7fffu + ((v.u >> 16) & 1u);
  return (ushort)(r >> 16);
}
__device__ __forceinline__ float bf2f(ushort h) {
  union { uint32_t u; float f; } v; v.u = ((uint32_t)h) << 16; return v.f;
}

// ---- numpy pairwise sum (blocksize 128, 8-way unrolled) of squares of 512 floats ----
__device__ __forceinline__ float np_pairwise_sq512(const float* buf, int lane) {
  const int blk = lane >> 3, j = lane & 7;
  const float* p = buf + ((lane < 32) ? (blk * 128 + j) : 0);
  float a = p[0];
  float acc = __fmul_rn(a, a);
#pragma unroll
  for (int i = 1; i < 16; ++i) {
    a = p[i * 8];
    acc = __fadd_rn(acc, __fmul_rn(a, a));
  }
  float s[4];
#pragma unroll
  for (int b = 0; b < 4; ++b) {
    const float p0 = __shfl(acc, b * 8 + 0), p1 = __shfl(acc, b * 8 + 1);
    const float p2 = __shfl(acc, b * 8 + 2), p3 = __shfl(acc, b * 8 + 3);
    const float p4 = __shfl(acc, b * 8 + 4), p5 = __shfl(acc, b * 8 + 5);
    const float p6 = __shfl(acc, b * 8 + 6), p7 = __shfl(acc, b * 8 + 7);
    s[b] = __fadd_rn(__fadd_rn(__fadd_rn(p0, p1), __fadd_rn(p2, p3)),
                     __fadd_rn(__fadd_rn(p4, p5), __fadd_rn(p6, p7)));
  }
  return __fadd_rn(__fadd_rn(s[0], s[1]), __fadd_rn(s[2], s[3]));
}

__global__ __launch_bounds__(64)
void cnorm_kernel(const float* __restrict__ cb, float* __restrict__ Cn) {
  const int row = blockIdx.x, lane = threadIdx.x;
  __shared__ float buf[DIM];
  const float* p = cb + (size_t)row * DIM + lane * 8;
  float4 a = *(const float4*)p, b = *(const float4*)(p + 4);
  *(float4*)&buf[lane * 8]     = a;
  *(float4*)&buf[lane * 8 + 4] = b;
  __syncthreads();
  const float v = np_pairwise_sq512(buf, lane);
  if (lane == 0) Cn[row] = v;
}

// ---- split fp32 array into bf16 hi/lo (used for codebooks AND for x at stage 0) ----
__global__ __launch_bounds__(256)
void cbsplit_kernel(const float* __restrict__ cb, ushort* __restrict__ hi, ushort* __restrict__ lo) {
  const size_t i = ((size_t)blockIdx.x * 256 + threadIdx.x) * 8;
  float4 a = *(const float4*)(cb + i), b = *(const float4*)(cb + i + 4);
  const float f[8] = {a.x, a.y, a.z, a.w, b.x, b.y, b.z, b.w};
  ushort h[8], l[8];
#pragma unroll
  for (int j = 0; j < 8; ++j) {
    h[j] = f2bf(f[j]);
    l[j] = f2bf(f[j] - bf2f(h[j]));
  }
  *(ushort4*)(hi + i)     = make_ushort4(h[0], h[1], h[2], h[3]);
  *(ushort4*)(hi + i + 4) = make_ushort4(h[4], h[5], h[6], h[7]);
  *(ushort4*)(lo + i)     = make_ushort4(l[0], l[1], l[2], l[3]);
  *(ushort4*)(lo + i + 4) = make_ushort4(l[4], l[5], l[6], l[7]);
}

__device__ __forceinline__ void top2_insert(float s, int c, float& v1, int& i1, float& v2, int& i2) {
  if (s > v1 || (s == v1 && c < i1)) { v2 = v1; i2 = i1; v1 = s; i1 = c; }
  else if (s > v2 || (s == v2 && c < i2)) { v2 = s; i2 = c; }
}

// ---------------- MFMA bf16x3 score + per-(rowtile,codetile) top-2 ----------------
// v9 = R6 with BOTH A and B double-buffered and prefetched one full kc ahead.
// R6's flaw: STAGE_B(kc) was issued+awaited in the SAME iteration -> vmcnt sat on
// B's L2 round-trip every kc. Now iteration kc issues STAGE(kc+1) for both streams
// (8 loads/thread), then s_waitcnt vmcnt(8) waits only kc's loads (issued one full
// iteration ago, latency covered by the intervening compute) and leaves kc+1's 8
// in flight across both raw s_barriers (T3-min + T4 counted vmcnt). buf[alt] is
// write-safe: its readers finished at the end-of-iter barrier of kc-1, and the
// STAGE is issued after that barrier. LDS 64KB+4KB -> 2 blocks/CU.
// Fragment math unchanged -> bit-identical scores.
__global__ __launch_bounds__(256, 2)
void argmax_kernel(const ushort* __restrict__ resh, const ushort* __restrict__ resl,
                   const ushort* __restrict__ cbh, const ushort* __restrict__ cbl,
                   const float* __restrict__ Cn, float4* __restrict__ partials)
{
  __shared__ ushort Ah[2][128 * 32], Al[2][128 * 32], Bh[2][128 * 32], Bl[2][128 * 32];
  __shared__ float4 mbuf[4][64];

  const int t    = threadIdx.x;
  const int lane = t & 63, w = t >> 6;
  const int ct = blockIdx.x & 15, rt = blockIdx.x >> 4;   // consecutive blocks share rt
  const int m0 = rt * 128, c0 = ct * 128;
  const int lm = lane & 15, lq = lane >> 4;
  const int wr = w >> 1, wc = w & 1;   // wave tile: rows [wr*64,+64), codes [wc*64,+64)

  // staging: chunk s=i*256+t -> LDS row s>>2, chunk s&3 (linear dest); source kseg
  // pre-swizzled (validated R2: 0 bank conflicts)
  const int arow  = t >> 2;
  const int bseg8 = (((t & 3) ^ ((t >> 3) & 3)) << 3);   // element offset of 16B chunk
  const int fcol  = ((lq ^ ((lm >> 1) & 3)) << 3);       // read-side swizzle

#define GLD(src, dst) \
  __builtin_amdgcn_global_load_lds((__attribute__((address_space(1))) void*)(src), \
                                   (__attribute__((address_space(3))) void*)(dst), 16, 0, 0)
#define STAGE_B(d, kc) do {                                                   \
    const int k0_ = (kc) * 32;                                                \
    _Pragma("unroll")                                                         \
    for (int i_ = 0; i_ < 2; ++i_) {                                          \
      const int s_ = i_ * 256 + t;                                            \
      const size_t g_ = (size_t)(c0 + i_ * 64 + arow) * DIM + k0_ + bseg8;    \
      GLD(cbh + g_, &Bh[d][s_ * 8]);                                          \
      GLD(cbl + g_, &Bl[d][s_ * 8]);                                          \
    }                                                                         \
  } while (0)
#define STAGE_A(d, kc) do {                                                   \
    const int k0_ = (kc) * 32;                                                \
    _Pragma("unroll")                                                         \
    for (int i_ = 0; i_ < 2; ++i_) {                                          \
      const int s_ = i_ * 256 + t;                                            \
      const size_t g_ = (size_t)(m0 + i_ * 64 + arow) * DIM + k0_ + bseg8;    \
      GLD(resh + g_, &Ah[d][s_ * 8]);                                         \
      GLD(resl + g_, &Al[d][s_ * 8]);                                         \
    }                                                                         \
  } while (0)

  f32x4 acc[4][4];   // [nt codes][mt rows]
#pragma unroll
  for (int nt = 0; nt < 4; ++nt)
#pragma unroll
    for (int mt = 0; mt < 4; ++mt) acc[nt][mt] = (f32x4){0.f, 0.f, 0.f, 0.f};

  STAGE_B(0, 0);   // prologue: kc=0 in flight (8 loads/thread)
  STAGE_A(0, 0);

  for (int kc = 0; kc < 16; ++kc) {
    const int cur = kc & 1;
    if (kc < 15) {
      STAGE_B(cur ^ 1, kc + 1);                          // prefetch next kc (both streams)
      STAGE_A(cur ^ 1, kc + 1);
      asm volatile("s_waitcnt vmcnt(8)" ::: "memory");   // kc's 8 done; kc+1's 8 in flight
    } else {
      asm volatile("s_waitcnt vmcnt(0)" ::: "memory");
    }
    __builtin_amdgcn_s_barrier();                        // all waves' staging visible
    asm volatile("" ::: "memory");
    // ---- fragments from buf[cur] (swizzled read) ----
    bf16x8 ch[4], cl[4];
#pragma unroll
    for (int nt = 0; nt < 4; ++nt) {
      const int o = (wc * 64 + nt * 16 + lm) * 32 + fcol;
      ch[nt] = *(bf16x8*)&Bh[cur][o];
      cl[nt] = *(bf16x8*)&Bl[cur][o];
    }
#pragma unroll
    for (int mt = 0; mt < 4; ++mt) {
      const int o = (wr * 64 + mt * 16 + lm) * 32 + fcol;
      const bf16x8 rh = *(bf16x8*)&Ah[cur][o];
      const bf16x8 rl = *(bf16x8*)&Al[cur][o];
      // swapped operands: D[code][row]; per-acc term order ch*rh, cl*rh, ch*rl (validated)
#pragma unroll
      for (int nt = 0; nt < 4; ++nt) {
        acc[nt][mt] = __builtin_amdgcn_mfma_f32_16x16x32_bf16(ch[nt], rh, acc[nt][mt], 0, 0, 0);
        acc[nt][mt] = __builtin_amdgcn_mfma_f32_16x16x32_bf16(cl[nt], rh, acc[nt][mt], 0, 0, 0);
        acc[nt][mt] = __builtin_amdgcn_mfma_f32_16x16x32_bf16(ch[nt], rl, acc[nt][mt], 0, 0, 0);
      }
    }
    asm volatile("" ::: "memory");
    __builtin_amdgcn_s_barrier();   // all waves done reading buf[cur] before overwrite
  }
#undef STAGE_A
#undef STAGE_B
#undef GLD

  // ---- epilogue: score = G - 0.5*||c||^2; codes in-lane (nt,r) + across lq ----
  float hc[4][4];
#pragma unroll
  for (int nt = 0; nt < 4; ++nt)
#pragma unroll
    for (int r = 0; r < 4; ++r)
      hc[nt][r] = 0.5f * Cn[c0 + wc * 64 + nt * 16 + lq * 4 + r];

#pragma unroll
  for (int mt = 0; mt < 4; ++mt) {   // wave-local row = mt*16 + lm
    float v1 = -3.4e38f, v2 = -3.4e38f;
    int   i1 = 0x7fffffff, i2 = 0x7fffffff;
#pragma unroll
    for (int nt = 0; nt < 4; ++nt)
#pragma unroll
      for (int r = 0; r < 4; ++r)
        top2_insert(acc[nt][mt][r] - hc[nt][r],
                    c0 + wc * 64 + nt * 16 + lq * 4 + r, v1, i1, v2, i2);
#pragma unroll
    for (int off = 16; off <= 32; off <<= 1) {   // merge lanes lm, lm+16, lm+32, lm+48
      const float ov1 = __shfl_xor(v1, off); const int oi1 = __shfl_xor(i1, off);
      const float ov2 = __shfl_xor(v2, off); const int oi2 = __shfl_xor(i2, off);
      top2_insert(ov1, oi1, v1, i1, v2, i2);
      top2_insert(ov2, oi2, v1, i1, v2, i2);
    }
    if (lq == 0) mbuf[w][mt * 16 + lm] = make_float4(v1, (float)i1, v2, (float)i2);
  }
  __syncthreads();
  if (t < 128) {   // row t: merge the 2 waves covering this row half
    const int half = t >> 6, rr = t & 63;
    float v1 = -3.4e38f, v2 = -3.4e38f;
    int   i1 = 0x7fffffff, i2 = 0x7fffffff;
#pragma unroll
    for (int ww = 0; ww < 2; ++ww) {
      float4 p = mbuf[half * 2 + ww][rr];
      top2_insert(p.x, (int)p.y, v1, i1, v2, i2);
      top2_insert(p.z, (int)p.w, v1, i1, v2, i2);
    }
    partials[(size_t)ct * N_ROWS + m0 + t] = make_float4(v1, (float)i1, v2, (float)i2);
  }
}

// ---- merge 16 code-tile partials per row -> idx + gap ----
__global__ __launch_bounds__(256)
void mergetop_kernel(const float4* __restrict__ partials, float* __restrict__ idx_out,
                     float* __restrict__ gap, int stage)
{
  const int row = blockIdx.x * 256 + threadIdx.x;
  float v1 = -3.4e38f, v2 = -3.4e38f;
  int   i1 = 0x7fffffff, i2 = 0x7fffffff;
#pragma unroll
  for (int ctt = 0; ctt < 16; ++ctt) {
    float4 p = partials[(size_t)ctt * N_ROWS + row];
    top2_insert(p.x, (int)p.y, v1, i1, v2, i2);
    top2_insert(p.z, (int)p.w, v1, i1, v2, i2);
  }
  idx_out[(size_t)row * NQ + stage] = (float)i1;
  gap[row] = v1 - v2;
}

// ---------------- np-fp32-mimic rescue (validated) ----------------
#define RESCUE_UNROLL 4

__global__ __launch_bounds__(256)
void rescue_kernel(const float* __restrict__ x, const float* __restrict__ cb,
                   const float* __restrict__ Cn, float* __restrict__ idxf,
                   const float* __restrict__ gap, int stage)
{
  const int row = blockIdx.x;
  if (gap[row] >= EPS_RESCUE) return;
  const int t = threadIdx.x;
  const int lane = t & 63, w = t >> 6;
  __shared__ float rs[DIM];
  __shared__ float sd[4];
  __shared__ int   si[4];

  // every wave computes the identical residual f[8] (deterministic replay)
  float f[8];
  {
    const float* xp = x + (size_t)row * DIM + lane * 8;
    float4 a = *(const float4*)xp, b = *(const float4*)(xp + 4);
    f[0]=a.x; f[1]=a.y; f[2]=a.z; f[3]=a.w; f[4]=b.x; f[5]=b.y; f[6]=b.z; f[7]=b.w;
  }
  for (int p = 0; p < stage; ++p) {
    const int ip = (int)idxf[(size_t)row * NQ + p];
    const float* cp = cb + ((size_t)p * NCODES + ip) * DIM + lane * 8;
    float4 a = *(const float4*)cp, b = *(const float4*)(cp + 4);
    const float q[8] = {a.x, a.y, a.z, a.w, b.x, b.y, b.z, b.w};
#pragma unroll
    for (int k = 0; k < 8; ++k) {
      const float tt = __fsub_rn(q[k], f[k]);   // sg(xq - r)
      const float xr = __fadd_rn(f[k], tt);     // x_res (STE)
      f[k] = __fsub_rn(f[k], xr);               // next residual
    }
  }
  if (w == 0) {
#pragma unroll
    for (int k = 0; k < 8; ++k) rs[lane * 8 + k] = f[k];
  }
  __syncthreads();
  const float Rn = np_pairwise_sq512(rs, lane);

  const float* cbs = cb + (size_t)stage * NCODES * DIM;
  const float* Cns = Cn + stage * NCODES;
  float dbest = 3.4e38f;
  int   ibest = 0x7fffffff;
  const int cbeg = w * (NCODES / 4);
  for (int cc = cbeg; cc < cbeg + NCODES / 4; cc += RESCUE_UNROLL) {
    float4 a[RESCUE_UNROLL], b[RESCUE_UNROLL];
#pragma unroll
    for (int u = 0; u < RESCUE_UNROLL; ++u) {
      const float* cp = cbs + (size_t)(cc + u) * DIM + lane * 8;
      a[u] = *(const float4*)cp;
      b[u] = *(const float4*)(cp + 4);
    }
    double s[RESCUE_UNROLL];
#pragma unroll
    for (int u = 0; u < RESCUE_UNROLL; ++u) {
      s[u] = (double)f[0] * a[u].x + (double)f[1] * a[u].y + (double)f[2] * a[u].z + (double)f[3] * a[u].w
           + (double)f[4] * b[u].x + (double)f[5] * b[u].y + (double)f[6] * b[u].z + (double)f[7] * b[u].w;
    }
#pragma unroll
    for (int off = 32; off; off >>= 1) {
#pragma unroll
      for (int u = 0; u < RESCUE_UNROLL; ++u) s[u] += __shfl_xor(s[u], off);
    }
#pragma unroll
    for (int u = 0; u < RESCUE_UNROLL; ++u) {
      const float G = (float)s[u];
      const float d = __fsub_rn(__fadd_rn(Rn, Cns[cc + u]), __fmul_rn(2.0f, G));
      if (d < dbest || (d == dbest && (cc + u) < ibest)) { dbest = d; ibest = cc + u; }
    }
  }
  if (lane == 0) { sd[w] = dbest; si[w] = ibest; }
  __syncthreads();
  if (t == 0) {
    float db = sd[0]; int ib = si[0];
#pragma unroll
    for (int ww = 1; ww < 4; ++ww) {
      if (sd[ww] < db || (sd[ww] == db && si[ww] < ib)) { db = sd[ww]; ib = si[ww]; }
    }
    idxf[(size_t)row * NQ + stage] = (float)ib;
  }
}

// ---------------- gather chosen code, accumulate x_q, loss, next-stage residual ----------------
__global__ __launch_bounds__(128)
void update_kernel(const float* __restrict__ x, float* __restrict__ xq_acc,
                   const float* __restrict__ cb, const float* __restrict__ idxf,
                   double* __restrict__ loss_arr,
                   ushort* __restrict__ resh, ushort* __restrict__ resl, int stage)
{
  const int n = blockIdx.x;
  const int t = threadIdx.x;
  const int idx = (int)idxf[(size_t)n * NQ + stage];
  const size_t g = (size_t)n * DIM + t * 4;

  float4 cv = *(const float4*)(cb + (size_t)idx * DIM + t * 4);
  float4 av;
  if (stage) av = *(const float4*)(xq_acc + g);
  else { av.x = 0.f; av.y = 0.f; av.z = 0.f; av.w = 0.f; }
  av.x += cv.x; av.y += cv.y; av.z += cv.z; av.w += cv.w;
  *(float4*)(xq_acc + g) = av;

  float4 xv = *(const float4*)(x + g);
  const float rx = xv.x - av.x, ry = xv.y - av.y, rz = xv.z - av.z, rw = xv.w - av.w;

  // next-stage residual bf16 hi/lo split (identical formula to cbsplit on x - xq_acc)
  {
    ushort4 h, l;
    h.x = f2bf(rx); l.x = f2bf(rx - bf2f(h.x));
    h.y = f2bf(ry); l.y = f2bf(ry - bf2f(h.y));
    h.z = f2bf(rz); l.z = f2bf(rz - bf2f(h.z));
    h.w = f2bf(rw); l.w = f2bf(rw - bf2f(h.w));
    *(ushort4*)(resh + g) = h;
    *(ushort4*)(resl + g) = l;
  }

  float s = rx * rx + ry * ry + rz * rz + rw * rw;
#pragma unroll
  for (int off = 32; off; off >>= 1) s += __shfl_down(s, off);
  __shared__ float wsum[2];
  if ((t & 63) == 0) wsum[t >> 6] = s;
  __syncthreads();
  if (t == 0) atomicAdd(&loss_arr[n & 511], (double)(wsum[0] + wsum[1]));  // 512-way fan-out
}

__global__ __launch_bounds__(64)
void finalize_kernel(const double* __restrict__ loss_arr, float* __restrict__ out_loss) {
  double s = 0.0;
  for (int i = threadIdx.x; i < 512; i += 64) s += loss_arr[i];
#pragma unroll
  for (int off = 32; off; off >>= 1) s += __shfl_down(s, off);
  if (threadIdx.x == 0)
    *out_loss = (float)(((1.0 + BETA) / ((double)NQ * (double)N_ROWS * (double)DIM)) * s);
}

extern "C" void kernel_launch(void* const* d_in, const int* in_sizes, int n_in,
                              void* d_out, int out_size, void* d_ws, size_t ws_size,
                              hipStream_t stream) {
  const float* x  = (const float*)d_in[0];
  const float* cb = (const float*)d_in[1];

  float* out_xq   = (float*)d_out;                       // [N, D]
  float* out_loss = out_xq + (size_t)N_ROWS * DIM;       // scalar
  float* out_idx  = out_loss + 1;                        // [N, Q] as float

  char* ws = (char*)d_ws;
  double* loss_arr = (double*)(ws + WS_LOSS);
  float*  Cn       = (float*) (ws + WS_CN);
  float*  gap      = (float*) (ws + WS_GAP);
  float4* partials = (float4*)(ws + WS_PART);
  ushort* cb_hi    = (ushort*)(ws + WS_CBH);
  ushort* cb_lo    = (ushort*)(ws + WS_CBL);
  ushort* res_hi   = (ushort*)(ws + WS_RESH);
  ushort* res_lo   = (ushort*)(ws + WS_RESL);

  hipMemsetAsync(ws + WS_LOSS, 0, 4096, stream);
  cbsplit_kernel<<<(NQ * NCODES * DIM) / 2048, 256, 0, stream>>>(cb, cb_hi, cb_lo);
  cbsplit_kernel<<<((size_t)N_ROWS * DIM) / 2048, 256, 0, stream>>>(x, res_hi, res_lo);  // stage-0 residual = x
  cnorm_kernel<<<NQ * NCODES, 64, 0, stream>>>(cb, Cn);

  for (int q = 0; q < NQ; ++q) {
    const float* cbq = cb + (size_t)q * NCODES * DIM;
    argmax_kernel<<<256 * 16, 256, 0, stream>>>(res_hi, res_lo,
                                                cb_hi + (size_t)q * NCODES * DIM,
                                                cb_lo + (size_t)q * NCODES * DIM,
                                                Cn + q * NCODES, partials);
    mergetop_kernel<<<N_ROWS / 256, 256, 0, stream>>>(partials, out_idx, gap, q);
    rescue_kernel<<<N_ROWS, 256, 0, stream>>>(x, cb, Cn, out_idx, gap, q);
    update_kernel<<<N_ROWS, 128, 0, stream>>>(x, out_xq, cbq, out_idx, loss_arr, res_hi, res_lo, q);
  }
  finalize_kernel<<<1, 64, 0, stream>>>(loss_arr, out_loss);
}

// Round 10
// 1278.173 us; speedup vs baseline: 3.2649x; 2.3654x over previous
//
#include <hip/hip_runtime.h>
#include <stdint.h>

#define N_ROWS 32768
#define DIM    512
#define NQ     4
#define NCODES 2048
#define BETA   0.25
#define EPS_RESCUE 0.02f   // MFMA-score gap below which the np-exact rescore kicks in

typedef __attribute__((ext_vector_type(8))) short bf16x8;
typedef __attribute__((ext_vector_type(4))) float f32x4;

// ---- ws layout (bytes) ---- (unchanged from the proven R6 layout; max 92,442,624 B)
#define WS_LOSS   0          // 512 doubles (4 KB)
#define WS_CN     4096       // Q*K floats (32 KB)
#define WS_GAP    36864      // N floats (128 KB) -- rescue-mode word, bit-packed
#define WS_PART   167936     // 16 * N float4 (8 MB): (v1, i1|i2<<16, v2, v3)
#define WS_CBH    8556544    // Q*K*D ushort (8 MB)
#define WS_CBL    16945152   // Q*K*D ushort (8 MB)
#define WS_RESH   25333760   // N*D ushort (32 MB) residual hi
#define WS_RESL   58888192   // N*D ushort (32 MB) residual lo

__device__ __forceinline__ ushort f2bf(float f) {
  union { float f; uint32_t u; } v; v.f = f;
  uint32_t r = v.u + 0x7fffu + ((v.u >> 16) & 1u);
  return (ushort)(r >> 16);
}
__device__ __forceinline__ float bf2f(ushort h) {
  union { uint32_t u; float f; } v; v.u = ((uint32_t)h) << 16; return v.f;
}

// ---- numpy pairwise sum (blocksize 128, 8-way unrolled) of squares of 512 floats ----
__device__ __forceinline__ float np_pairwise_sq512(const float* buf, int lane) {
  const int blk = lane >> 3, j = lane & 7;
  const float* p = buf + ((lane < 32) ? (blk * 128 + j) : 0);
  float a = p[0];
  float acc = __fmul_rn(a, a);
#pragma unroll
  for (int i = 1; i < 16; ++i) {
    a = p[i * 8];
    acc = __fadd_rn(acc, __fmul_rn(a, a));
  }
  float s[4];
#pragma unroll
  for (int b = 0; b < 4; ++b) {
    const float p0 = __shfl(acc, b * 8 + 0), p1 = __shfl(acc, b * 8 + 1);
    const float p2 = __shfl(acc, b * 8 + 2), p3 = __shfl(acc, b * 8 + 3);
    const float p4 = __shfl(acc, b * 8 + 4), p5 = __shfl(acc, b * 8 + 5);
    const float p6 = __shfl(acc, b * 8 + 6), p7 = __shfl(acc, b * 8 + 7);
    s[b] = __fadd_rn(__fadd_rn(__fadd_rn(p0, p1), __fadd_rn(p2, p3)),
                     __fadd_rn(__fadd_rn(p4, p5), __fadd_rn(p6, p7)));
  }
  return __fadd_rn(__fadd_rn(s[0], s[1]), __fadd_rn(s[2], s[3]));
}

__global__ __launch_bounds__(64)
void cnorm_kernel(const float* __restrict__ cb, float* __restrict__ Cn) {
  const int row = blockIdx.x, lane = threadIdx.x;
  __shared__ float buf[DIM];
  const float* p = cb + (size_t)row * DIM + lane * 8;
  float4 a = *(const float4*)p, b = *(const float4*)(p + 4);
  *(float4*)&buf[lane * 8]     = a;
  *(float4*)&buf[lane * 8 + 4] = b;
  __syncthreads();
  const float v = np_pairwise_sq512(buf, lane);
  if (lane == 0) Cn[row] = v;
}

// ---- split fp32 array into bf16 hi/lo (used for codebooks AND for x at stage 0) ----
__global__ __launch_bounds__(256)
void cbsplit_kernel(const float* __restrict__ cb, ushort* __restrict__ hi, ushort* __restrict__ lo) {
  const size_t i = ((size_t)blockIdx.x * 256 + threadIdx.x) * 8;
  float4 a = *(const float4*)(cb + i), b = *(const float4*)(cb + i + 4);
  const float f[8] = {a.x, a.y, a.z, a.w, b.x, b.y, b.z, b.w};
  ushort h[8], l[8];
#pragma unroll
  for (int j = 0; j < 8; ++j) {
    h[j] = f2bf(f[j]);
    l[j] = f2bf(f[j] - bf2f(h[j]));
  }
  *(ushort4*)(hi + i)     = make_ushort4(h[0], h[1], h[2], h[3]);
  *(ushort4*)(hi + i + 4) = make_ushort4(h[4], h[5], h[6], h[7]);
  *(ushort4*)(lo + i)     = make_ushort4(l[0], l[1], l[2], l[3]);
  *(ushort4*)(lo + i + 4) = make_ushort4(l[4], l[5], l[6], l[7]);
}

__device__ __forceinline__ void top2_insert(float s, int c, float& v1, int& i1, float& v2, int& i2) {
  if (s > v1 || (s == v1 && c < i1)) { v2 = v1; i2 = i1; v1 = s; i1 = c; }
  else if (s > v2 || (s == v2 && c < i2)) { v2 = s; i2 = c; }
}

// top-3 insert: v1/v2 logic is IDENTICAL to top2_insert (so i1/i2 stay bit-identical
// to the validated path); v3 is value-only. Dummy-index (INT_MAX) inserts of other
// lanes' v3 cannot displace v1/v2: strict > required, equal-value blocked by c<i rule.
__device__ __forceinline__ void top3_insert(float s, int c, float& v1, int& i1,
                                            float& v2, int& i2, float& v3) {
  if (s > v1 || (s == v1 && c < i1)) { v3 = v2; v2 = v1; i2 = i1; v1 = s; i1 = c; }
  else if (s > v2 || (s == v2 && c < i2)) { v3 = v2; v2 = s; i2 = c; }
  else if (s > v3) { v3 = s; }
}

__device__ __forceinline__ float pack_ii(int i1, int i2) {
  return __uint_as_float(((uint32_t)i1 & 0xffffu) | ((uint32_t)i2 << 16));
}

// ---------------- MFMA bf16x3 score + per-(rowtile,codetile) top-2 (+v3) ----------------
// v11: main loop = R4's proven single-buffered 2-barrier 128x128 structure (453us;
// R3/R6/R8 pipelining variants regressed or tied -> local ceiling). Epilogue also
// tracks the per-128-code-tile 3rd-best VALUE, packed into partials.w (indices
// i1,i2 < 2048 pack losslessly into partials.y bits) -> NO workspace growth vs the
// proven layout. Fragment math unchanged -> scores bit-identical.
__global__ __launch_bounds__(256, 3)
void argmax_kernel(const ushort* __restrict__ resh, const ushort* __restrict__ resl,
                   const ushort* __restrict__ cbh, const ushort* __restrict__ cbl,
                   const float* __restrict__ Cn, float4* __restrict__ partials)
{
  __shared__ ushort Ah[128 * 32], Al[128 * 32], Bh[128 * 32], Bl[128 * 32];
  __shared__ float4 mbuf[4][64];   // (v1, packed(i1,i2), v2, v3)

  const int t    = threadIdx.x;
  const int lane = t & 63, w = t >> 6;
  const int ct = blockIdx.x & 15, rt = blockIdx.x >> 4;   // consecutive blocks share rt
  const int m0 = rt * 128, c0 = ct * 128;
  const int lm = lane & 15, lq = lane >> 4;
  const int wr = w >> 1, wc = w & 1;   // wave tile: rows [wr*64,+64), codes [wc*64,+64)

  // staging: chunk s=i*256+t -> LDS row s>>2, chunk s&3 (linear dest); source kseg
  // pre-swizzled (validated R2: 0 bank conflicts)
  const int arow  = t >> 2;
  const int bseg8 = (((t & 3) ^ ((t >> 3) & 3)) << 3);   // element offset of 16B chunk
  const int fcol  = ((lq ^ ((lm >> 1) & 3)) << 3);       // read-side swizzle

#define GLD(src, dst) \
  __builtin_amdgcn_global_load_lds((__attribute__((address_space(1))) void*)(src), \
                                   (__attribute__((address_space(3))) void*)(dst), 16, 0, 0)

  f32x4 acc[4][4];   // [nt codes][mt rows]
#pragma unroll
  for (int nt = 0; nt < 4; ++nt)
#pragma unroll
    for (int mt = 0; mt < 4; ++mt) acc[nt][mt] = (f32x4){0.f, 0.f, 0.f, 0.f};

  for (int kc = 0; kc < 16; ++kc) {
    const int k0 = kc * 32;
    __syncthreads();
    // ---- stage A (128 rows) + B (128 codes), hi+lo: 8 x 16B per thread ----
#pragma unroll
    for (int i = 0; i < 2; ++i) {
      const int s = i * 256 + t;
      const size_t gB = (size_t)(c0 + i * 64 + arow) * DIM + k0 + bseg8;
      GLD(cbh + gB, &Bh[s * 8]);
      GLD(cbl + gB, &Bl[s * 8]);
      const size_t gA = (size_t)(m0 + i * 64 + arow) * DIM + k0 + bseg8;
      GLD(resh + gA, &Ah[s * 8]);
      GLD(resl + gA, &Al[s * 8]);
    }
    __syncthreads();   // drains vmcnt (global_load_lds)
    // ---- fragments (swizzled read) ----
    bf16x8 ch[4], cl[4];
#pragma unroll
    for (int nt = 0; nt < 4; ++nt) {
      const int o = (wc * 64 + nt * 16 + lm) * 32 + fcol;
      ch[nt] = *(bf16x8*)&Bh[o];
      cl[nt] = *(bf16x8*)&Bl[o];
    }
#pragma unroll
    for (int mt = 0; mt < 4; ++mt) {
      const int o = (wr * 64 + mt * 16 + lm) * 32 + fcol;
      const bf16x8 rh = *(bf16x8*)&Ah[o];
      const bf16x8 rl = *(bf16x8*)&Al[o];
      // swapped operands: D[code][row]; per-acc term order ch*rh, cl*rh, ch*rl (validated)
#pragma unroll
      for (int nt = 0; nt < 4; ++nt) {
        acc[nt][mt] = __builtin_amdgcn_mfma_f32_16x16x32_bf16(ch[nt], rh, acc[nt][mt], 0, 0, 0);
        acc[nt][mt] = __builtin_amdgcn_mfma_f32_16x16x32_bf16(cl[nt], rh, acc[nt][mt], 0, 0, 0);
        acc[nt][mt] = __builtin_amdgcn_mfma_f32_16x16x32_bf16(ch[nt], rl, acc[nt][mt], 0, 0, 0);
      }
    }
  }
#undef GLD

  // ---- epilogue: score = G - 0.5*||c||^2; codes in-lane (nt,r) + across lq ----
  float hc[4][4];
#pragma unroll
  for (int nt = 0; nt < 4; ++nt)
#pragma unroll
    for (int r = 0; r < 4; ++r)
      hc[nt][r] = 0.5f * Cn[c0 + wc * 64 + nt * 16 + lq * 4 + r];

#pragma unroll
  for (int mt = 0; mt < 4; ++mt) {   // wave-local row = mt*16 + lm
    float v1 = -3.4e38f, v2 = -3.4e38f, v3 = -3.4e38f;
    int   i1 = 0x7fffffff, i2 = 0x7fffffff;
#pragma unroll
    for (int nt = 0; nt < 4; ++nt)
#pragma unroll
      for (int r = 0; r < 4; ++r)
        top3_insert(acc[nt][mt][r] - hc[nt][r],
                    c0 + wc * 64 + nt * 16 + lq * 4 + r, v1, i1, v2, i2, v3);
#pragma unroll
    for (int off = 16; off <= 32; off <<= 1) {   // merge lanes lm, lm+16, lm+32, lm+48
      const float ov1 = __shfl_xor(v1, off); const int oi1 = __shfl_xor(i1, off);
      const float ov2 = __shfl_xor(v2, off); const int oi2 = __shfl_xor(i2, off);
      const float ov3 = __shfl_xor(v3, off);
      top3_insert(ov1, oi1, v1, i1, v2, i2, v3);
      top3_insert(ov2, oi2, v1, i1, v2, i2, v3);
      top3_insert(ov3, 0x7fffffff, v1, i1, v2, i2, v3);
    }
    if (lq == 0) mbuf[w][mt * 16 + lm] = make_float4(v1, pack_ii(i1, i2), v2, v3);
  }
  __syncthreads();
  if (t < 128) {   // row t: merge the 2 waves covering this row half
    const int half = t >> 6, rr = t & 63;
    float v1 = -3.4e38f, v2 = -3.4e38f, v3 = -3.4e38f;
    int   i1 = 0x7fffffff, i2 = 0x7fffffff;
#pragma unroll
    for (int ww = 0; ww < 2; ++ww) {
      float4 p = mbuf[half * 2 + ww][rr];
      const uint32_t bits = __float_as_uint(p.y);
      top3_insert(p.x, (int)(bits & 0xffffu), v1, i1, v2, i2, v3);
      top3_insert(p.z, (int)(bits >> 16),     v1, i1, v2, i2, v3);
      top3_insert(p.w, 0x7fffffff, v1, i1, v2, i2, v3);
    }
    partials[(size_t)ct * N_ROWS + m0 + t] = make_float4(v1, pack_ii(i1, i2), v2, v3);
  }
}

// ---- merge 16 code-tile partials per row -> idx + rescue mode (bit-packed) ----
// mode 2: gap >= EPS (identical to validated skip condition).
// mode 1: codes with mfma-score >= v1-EPS number <=4 AND no tile hides a 3rd
//         in-window entry (tile-v3 < window) -> candidate set provably complete.
//         Candidates encoded as (tile,slot) descriptors (5 bits each) in the word.
// mode 0: otherwise -> full np-exact scan (validated path).
__global__ __launch_bounds__(256)
void mergetop_kernel(const float4* __restrict__ partials, float* __restrict__ idx_out,
                     float* __restrict__ gap, int stage)
{
  const int row = blockIdx.x * 256 + threadIdx.x;
  float v1 = -3.4e38f, v2 = -3.4e38f, vm3 = -3.4e38f;
  int   i1 = 0x7fffffff, i2 = 0x7fffffff;
  float4 ptile[16];
#pragma unroll
  for (int ctt = 0; ctt < 16; ++ctt) {
    ptile[ctt] = partials[(size_t)ctt * N_ROWS + row];
    const uint32_t bits = __float_as_uint(ptile[ctt].y);
    top2_insert(ptile[ctt].x, (int)(bits & 0xffffu), v1, i1, v2, i2);
    top2_insert(ptile[ctt].z, (int)(bits >> 16),     v1, i1, v2, i2);
    vm3 = fmaxf(vm3, ptile[ctt].w);
  }
  idx_out[(size_t)row * NQ + stage] = (float)i1;
  if (v1 - v2 >= EPS_RESCUE) { gap[row] = __uint_as_float(2u); return; }
  const float window = v1 - EPS_RESCUE;
  uint32_t cnt = 0, descs = 0;
#pragma unroll
  for (int ctt = 0; ctt < 16; ++ctt) {
    if (ptile[ctt].x >= window) { if (cnt < 4) descs |= (uint32_t)(ctt * 2 + 0) << (5 * cnt); ++cnt; }
    if (ptile[ctt].z >= window) { if (cnt < 4) descs |= (uint32_t)(ctt * 2 + 1) << (5 * cnt); ++cnt; }
  }
  if (cnt > 4 || vm3 >= window) { gap[row] = __uint_as_float(0u); return; }
  gap[row] = __uint_as_float(1u | (cnt << 2) | (descs << 5));
}

// ---------------- np-fp32-mimic rescue: candidate mode (fast) or full scan ----------------
#define RESCUE_UNROLL 4

__global__ __launch_bounds__(256)
void rescue_kernel(const float* __restrict__ x, const float* __restrict__ cb,
                   const float* __restrict__ Cn, float* __restrict__ idxf,
                   const float* __restrict__ gap, const float4* __restrict__ partials,
                   int stage)
{
  const int row = blockIdx.x;
  const uint32_t g = __float_as_uint(gap[row]);
  const uint32_t mode = g & 3u;
  if (mode == 2u) return;
  const int t = threadIdx.x;
  const int lane = t & 63, w = t >> 6;
  __shared__ float rs[DIM];
  __shared__ float sd[4];
  __shared__ int   si[4];

  // every wave computes the identical residual f[8] (deterministic replay)
  float f[8];
  {
    const float* xp = x + (size_t)row * DIM + lane * 8;
    float4 a = *(const float4*)xp, b = *(const float4*)(xp + 4);
    f[0]=a.x; f[1]=a.y; f[2]=a.z; f[3]=a.w; f[4]=b.x; f[5]=b.y; f[6]=b.z; f[7]=b.w;
  }
  for (int p = 0; p < stage; ++p) {
    const int ip = (int)idxf[(size_t)row * NQ + p];
    const float* cp = cb + ((size_t)p * NCODES + ip) * DIM + lane * 8;
    float4 a = *(const float4*)cp, b = *(const float4*)(cp + 4);
    const float q[8] = {a.x, a.y, a.z, a.w, b.x, b.y, b.z, b.w};
#pragma unroll
    for (int k = 0; k < 8; ++k) {
      const float tt = __fsub_rn(q[k], f[k]);   // sg(xq - r)
      const float xr = __fadd_rn(f[k], tt);     // x_res (STE)
      f[k] = __fsub_rn(f[k], xr);               // next residual
    }
  }
  if (w == 0) {
#pragma unroll
    for (int k = 0; k < 8; ++k) rs[lane * 8 + k] = f[k];
  }
  __syncthreads();
  const float Rn = np_pairwise_sq512(rs, lane);

  const float* cbs = cb + (size_t)stage * NCODES * DIM;
  const float* Cns = Cn + stage * NCODES;

  if (mode == 1u) {          // candidate rescore: <=4 codes, np-exact arithmetic
    if (w == 0) {
      const int cnt = (int)((g >> 2) & 7u);
      float dbest = 3.4e38f;
      int   ibest = 0x7fffffff;
      for (int u = 0; u < cnt; ++u) {
        const uint32_t d5 = (g >> (5 + 5 * u)) & 31u;
        const float4 p = partials[(size_t)(d5 >> 1) * N_ROWS + row];
        const uint32_t bits = __float_as_uint(p.y);
        const int c = (int)((d5 & 1u) ? (bits >> 16) : (bits & 0xffffu));
        const float* cp = cbs + (size_t)c * DIM + lane * 8;
        float4 a = *(const float4*)cp, b = *(const float4*)(cp + 4);
        double s = (double)f[0] * a.x + (double)f[1] * a.y + (double)f[2] * a.z + (double)f[3] * a.w
                 + (double)f[4] * b.x + (double)f[5] * b.y + (double)f[6] * b.z + (double)f[7] * b.w;
#pragma unroll
        for (int off = 32; off; off >>= 1) s += __shfl_xor(s, off);
        const float G = (float)s;
        const float d = __fsub_rn(__fadd_rn(Rn, Cns[c]), __fmul_rn(2.0f, G));
        if (d < dbest || (d == dbest && c < ibest)) { dbest = d; ibest = c; }
      }
      if (lane == 0) idxf[(size_t)row * NQ + stage] = (float)ibest;
    }
    return;
  }

  // ---- mode 0: full scan (validated 4-wave path) ----
  float dbest = 3.4e38f;
  int   ibest = 0x7fffffff;
  const int cbeg = w * (NCODES / 4);
  for (int cc = cbeg; cc < cbeg + NCODES / 4; cc += RESCUE_UNROLL) {
    float4 a[RESCUE_UNROLL], b[RESCUE_UNROLL];
#pragma unroll
    for (int u = 0; u < RESCUE_UNROLL; ++u) {
      const float* cp = cbs + (size_t)(cc + u) * DIM + lane * 8;
      a[u] = *(const float4*)cp;
      b[u] = *(const float4*)(cp + 4);
    }
    double s[RESCUE_UNROLL];
#pragma unroll
    for (int u = 0; u < RESCUE_UNROLL; ++u) {
      s[u] = (double)f[0] * a[u].x + (double)f[1] * a[u].y + (double)f[2] * a[u].z + (double)f[3] * a[u].w
           + (double)f[4] * b[u].x + (double)f[5] * b[u].y + (double)f[6] * b[u].z + (double)f[7] * b[u].w;
    }
#pragma unroll
    for (int off = 32; off; off >>= 1) {
#pragma unroll
      for (int u = 0; u < RESCUE_UNROLL; ++u) s[u] += __shfl_xor(s[u], off);
    }
#pragma unroll
    for (int u = 0; u < RESCUE_UNROLL; ++u) {
      const float G = (float)s[u];
      const float d = __fsub_rn(__fadd_rn(Rn, Cns[cc + u]), __fmul_rn(2.0f, G));
      if (d < dbest || (d == dbest && (cc + u) < ibest)) { dbest = d; ibest = cc + u; }
    }
  }
  if (lane == 0) { sd[w] = dbest; si[w] = ibest; }
  __syncthreads();
  if (t == 0) {
    float db = sd[0]; int ib = si[0];
#pragma unroll
    for (int ww = 1; ww < 4; ++ww) {
      if (sd[ww] < db || (sd[ww] == db && si[ww] < ib)) { db = sd[ww]; ib = si[ww]; }
    }
    idxf[(size_t)row * NQ + stage] = (float)ib;
  }
}

// ---------------- gather chosen code, accumulate x_q, loss, next-stage residual ----------------
__global__ __launch_bounds__(128)
void update_kernel(const float* __restrict__ x, float* __restrict__ xq_acc,
                   const float* __restrict__ cb, const float* __restrict__ idxf,
                   double* __restrict__ loss_arr,
                   ushort* __restrict__ resh, ushort* __restrict__ resl, int stage)
{
  const int n = blockIdx.x;
  const int t = threadIdx.x;
  const int idx = (int)idxf[(size_t)n * NQ + stage];
  const size_t g = (size_t)n * DIM + t * 4;

  float4 cv = *(const float4*)(cb + (size_t)idx * DIM + t * 4);
  float4 av;
  if (stage) av = *(const float4*)(xq_acc + g);
  else { av.x = 0.f; av.y = 0.f; av.z = 0.f; av.w = 0.f; }
  av.x += cv.x; av.y += cv.y; av.z += cv.z; av.w += cv.w;
  *(float4*)(xq_acc + g) = av;

  float4 xv = *(const float4*)(x + g);
  const float rx = xv.x - av.x, ry = xv.y - av.y, rz = xv.z - av.z, rw = xv.w - av.w;

  // next-stage residual bf16 hi/lo split (identical formula to cbsplit on x - xq_acc)
  {
    ushort4 h, l;
    h.x = f2bf(rx); l.x = f2bf(rx - bf2f(h.x));
    h.y = f2bf(ry); l.y = f2bf(ry - bf2f(h.y));
    h.z = f2bf(rz); l.z = f2bf(rz - bf2f(h.z));
    h.w = f2bf(rw); l.w = f2bf(rw - bf2f(h.w));
    *(ushort4*)(resh + g) = h;
    *(ushort4*)(resl + g) = l;
  }

  float s = rx * rx + ry * ry + rz * rz + rw * rw;
#pragma unroll
  for (int off = 32; off; off >>= 1) s += __shfl_down(s, off);
  __shared__ float wsum[2];
  if ((t & 63) == 0) wsum[t >> 6] = s;
  __syncthreads();
  if (t == 0) atomicAdd(&loss_arr[n & 511], (double)(wsum[0] + wsum[1]));  // 512-way fan-out
}

__global__ __launch_bounds__(64)
void finalize_kernel(const double* __restrict__ loss_arr, float* __restrict__ out_loss) {
  double s = 0.0;
  for (int i = threadIdx.x; i < 512; i += 64) s += loss_arr[i];
#pragma unroll
  for (int off = 32; off; off >>= 1) s += __shfl_down(s, off);
  if (threadIdx.x == 0)
    *out_loss = (float)(((1.0 + BETA) / ((double)NQ * (double)N_ROWS * (double)DIM)) * s);
}

extern "C" void kernel_launch(void* const* d_in, const int* in_sizes, int n_in,
                              void* d_out, int out_size, void* d_ws, size_t ws_size,
                              hipStream_t stream) {
  const float* x  = (const float*)d_in[0];
  const float* cb = (const float*)d_in[1];

  float* out_xq   = (float*)d_out;                       // [N, D]
  float* out_loss = out_xq + (size_t)N_ROWS * DIM;       // scalar
  float* out_idx  = out_loss + 1;                        // [N, Q] as float

  char* ws = (char*)d_ws;
  double* loss_arr = (double*)(ws + WS_LOSS);
  float*  Cn       = (float*) (ws + WS_CN);
  float*  gap      = (float*) (ws + WS_GAP);
  float4* partials = (float4*)(ws + WS_PART);
  ushort* cb_hi    = (ushort*)(ws + WS_CBH);
  ushort* cb_lo    = (ushort*)(ws + WS_CBL);
  ushort* res_hi   = (ushort*)(ws + WS_RESH);
  ushort* res_lo   = (ushort*)(ws + WS_RESL);

  hipMemsetAsync(ws + WS_LOSS, 0, 4096, stream);
  cbsplit_kernel<<<(NQ * NCODES * DIM) / 2048, 256, 0, stream>>>(cb, cb_hi, cb_lo);
  cbsplit_kernel<<<((size_t)N_ROWS * DIM) / 2048, 256, 0, stream>>>(x, res_hi, res_lo);  // stage-0 residual = x
  cnorm_kernel<<<NQ * NCODES, 64, 0, stream>>>(cb, Cn);

  for (int q = 0; q < NQ; ++q) {
    const float* cbq = cb + (size_t)q * NCODES * DIM;
    argmax_kernel<<<256 * 16, 256, 0, stream>>>(res_hi, res_lo,
                                                cb_hi + (size_t)q * NCODES * DIM,
                                                cb_lo + (size_t)q * NCODES * DIM,
                                                Cn + q * NCODES, partials);
    mergetop_kernel<<<N_ROWS / 256, 256, 0, stream>>>(partials, out_idx, gap, q);
    rescue_kernel<<<N_ROWS, 256, 0, stream>>>(x, cb, Cn, out_idx, gap, partials, q);
    update_kernel<<<N_ROWS, 128, 0, stream>>>(x, out_xq, cbq, out_idx, loss_arr, res_hi, res_lo, q);
  }
  finalize_kernel<<<1, 64, 0, stream>>>(loss_arr, out_loss);
}

// Round 11
// 1252.691 us; speedup vs baseline: 3.3314x; 1.0203x over previous
//
#include <hip/hip_runtime.h>
#include <stdint.h>

#define N_ROWS 32768
#define DIM    512
#define NQ     4
#define NCODES 2048
#define BETA   0.25
#define EPS_RESCUE 0.02f   // MFMA-score gap below which the np-exact rescore kicks in

typedef __attribute__((ext_vector_type(8))) short bf16x8;
typedef __attribute__((ext_vector_type(4))) float f32x4;

// ---- ws layout (bytes) ---- (unchanged from the proven R6 layout; max 92,442,624 B)
#define WS_LOSS   0          // 512 doubles (4 KB)
#define WS_CN     4096       // Q*K floats (32 KB)
#define WS_GAP    36864      // N floats (128 KB) -- rescue-mode word, bit-packed
#define WS_PART   167936     // 16 * N float4 (8 MB): (v1, i1|i2<<16, v2, v3)
#define WS_CBH    8556544    // Q*K*D ushort (8 MB)
#define WS_CBL    16945152   // Q*K*D ushort (8 MB)
#define WS_RESH   25333760   // N*D ushort (32 MB) residual hi
#define WS_RESL   58888192   // N*D ushort (32 MB) residual lo

__device__ __forceinline__ ushort f2bf(float f) {
  union { float f; uint32_t u; } v; v.f = f;
  uint32_t r = v.u + 0x7fffu + ((v.u >> 16) & 1u);
  return (ushort)(r >> 16);
}
__device__ __forceinline__ float bf2f(ushort h) {
  union { uint32_t u; float f; } v; v.u = ((uint32_t)h) << 16; return v.f;
}

// ---- numpy pairwise sum (blocksize 128, 8-way unrolled) of squares of 512 floats ----
__device__ __forceinline__ float np_pairwise_sq512(const float* buf, int lane) {
  const int blk = lane >> 3, j = lane & 7;
  const float* p = buf + ((lane < 32) ? (blk * 128 + j) : 0);
  float a = p[0];
  float acc = __fmul_rn(a, a);
#pragma unroll
  for (int i = 1; i < 16; ++i) {
    a = p[i * 8];
    acc = __fadd_rn(acc, __fmul_rn(a, a));
  }
  float s[4];
#pragma unroll
  for (int b = 0; b < 4; ++b) {
    const float p0 = __shfl(acc, b * 8 + 0), p1 = __shfl(acc, b * 8 + 1);
    const float p2 = __shfl(acc, b * 8 + 2), p3 = __shfl(acc, b * 8 + 3);
    const float p4 = __shfl(acc, b * 8 + 4), p5 = __shfl(acc, b * 8 + 5);
    const float p6 = __shfl(acc, b * 8 + 6), p7 = __shfl(acc, b * 8 + 7);
    s[b] = __fadd_rn(__fadd_rn(__fadd_rn(p0, p1), __fadd_rn(p2, p3)),
                     __fadd_rn(__fadd_rn(p4, p5), __fadd_rn(p6, p7)));
  }
  return __fadd_rn(__fadd_rn(s[0], s[1]), __fadd_rn(s[2], s[3]));
}

__global__ __launch_bounds__(64)
void cnorm_kernel(const float* __restrict__ cb, float* __restrict__ Cn) {
  const int row = blockIdx.x, lane = threadIdx.x;
  __shared__ float buf[DIM];
  const float* p = cb + (size_t)row * DIM + lane * 8;
  float4 a = *(const float4*)p, b = *(const float4*)(p + 4);
  *(float4*)&buf[lane * 8]     = a;
  *(float4*)&buf[lane * 8 + 4] = b;
  __syncthreads();
  const float v = np_pairwise_sq512(buf, lane);
  if (lane == 0) Cn[row] = v;
}

// ---- split fp32 array into bf16 hi/lo (used for codebooks AND for x at stage 0) ----
__global__ __launch_bounds__(256)
void cbsplit_kernel(const float* __restrict__ cb, ushort* __restrict__ hi, ushort* __restrict__ lo) {
  const size_t i = ((size_t)blockIdx.x * 256 + threadIdx.x) * 8;
  float4 a = *(const float4*)(cb + i), b = *(const float4*)(cb + i + 4);
  const float f[8] = {a.x, a.y, a.z, a.w, b.x, b.y, b.z, b.w};
  ushort h[8], l[8];
#pragma unroll
  for (int j = 0; j < 8; ++j) {
    h[j] = f2bf(f[j]);
    l[j] = f2bf(f[j] - bf2f(h[j]));
  }
  *(ushort4*)(hi + i)     = make_ushort4(h[0], h[1], h[2], h[3]);
  *(ushort4*)(hi + i + 4) = make_ushort4(h[4], h[5], h[6], h[7]);
  *(ushort4*)(lo + i)     = make_ushort4(l[0], l[1], l[2], l[3]);
  *(ushort4*)(lo + i + 4) = make_ushort4(l[4], l[5], l[6], l[7]);
}

__device__ __forceinline__ void top2_insert(float s, int c, float& v1, int& i1, float& v2, int& i2) {
  if (s > v1 || (s == v1 && c < i1)) { v2 = v1; i2 = i1; v1 = s; i1 = c; }
  else if (s > v2 || (s == v2 && c < i2)) { v2 = s; i2 = c; }
}

// top-3 insert: v1/v2 logic is IDENTICAL to top2_insert (so i1/i2 stay bit-identical
// to the validated path); v3 is value-only. Dummy-index (INT_MAX) inserts of other
// lanes' v3 cannot displace v1/v2: strict > required, equal-value blocked by c<i rule.
__device__ __forceinline__ void top3_insert(float s, int c, float& v1, int& i1,
                                            float& v2, int& i2, float& v3) {
  if (s > v1 || (s == v1 && c < i1)) { v3 = v2; v2 = v1; i2 = i1; v1 = s; i1 = c; }
  else if (s > v2 || (s == v2 && c < i2)) { v3 = v2; v2 = s; i2 = c; }
  else if (s > v3) { v3 = s; }
}

__device__ __forceinline__ float pack_ii(int i1, int i2) {
  return __uint_as_float(((uint32_t)i1 & 0xffffu) | ((uint32_t)i2 << 16));
}

// ---------------- MFMA bf16x3 score + per-(rowtile,codetile) top-2 (+v3) ----------------
// v12 = v11 (R10, 1278us total) with the kc loop FULLY UNROLLED and the 8 staging
// base pointers hoisted: per-kc global addresses become base + kc*64B (constant),
// killing the per-iteration v_mad/lshl_add address chains that drove VALUBusy=34%.
// Staging maps, swizzle, fragment reads, MFMA term order, epilogue all unchanged
// -> bit-identical outputs.
__global__ __launch_bounds__(256, 3)
void argmax_kernel(const ushort* __restrict__ resh, const ushort* __restrict__ resl,
                   const ushort* __restrict__ cbh, const ushort* __restrict__ cbl,
                   const float* __restrict__ Cn, float4* __restrict__ partials)
{
  __shared__ ushort Ah[128 * 32], Al[128 * 32], Bh[128 * 32], Bl[128 * 32];
  __shared__ float4 mbuf[4][64];   // (v1, packed(i1,i2), v2, v3)

  const int t    = threadIdx.x;
  const int lane = t & 63, w = t >> 6;
  const int ct = blockIdx.x & 15, rt = blockIdx.x >> 4;   // consecutive blocks share rt
  const int m0 = rt * 128, c0 = ct * 128;
  const int lm = lane & 15, lq = lane >> 4;
  const int wr = w >> 1, wc = w & 1;   // wave tile: rows [wr*64,+64), codes [wc*64,+64)

  // staging: chunk s=i*256+t -> LDS row s>>2, chunk s&3 (linear dest); source kseg
  // pre-swizzled (validated R2: 0 bank conflicts)
  const int arow  = t >> 2;
  const int bseg8 = (((t & 3) ^ ((t >> 3) & 3)) << 3);   // element offset of 16B chunk
  const int fcol  = ((lq ^ ((lm >> 1) & 3)) << 3);       // read-side swizzle

  // hoisted staging base pointers (advance by kc*32 ushorts per K-chunk)
  const ushort* pB0h = cbh  + (size_t)(c0 + arow)      * DIM + bseg8;
  const ushort* pB0l = cbl  + (size_t)(c0 + arow)      * DIM + bseg8;
  const ushort* pB1h = cbh  + (size_t)(c0 + 64 + arow) * DIM + bseg8;
  const ushort* pB1l = cbl  + (size_t)(c0 + 64 + arow) * DIM + bseg8;
  const ushort* pA0h = resh + (size_t)(m0 + arow)      * DIM + bseg8;
  const ushort* pA0l = resl + (size_t)(m0 + arow)      * DIM + bseg8;
  const ushort* pA1h = resh + (size_t)(m0 + 64 + arow) * DIM + bseg8;
  const ushort* pA1l = resl + (size_t)(m0 + 64 + arow) * DIM + bseg8;

#define GLD(src, dst) \
  __builtin_amdgcn_global_load_lds((__attribute__((address_space(1))) void*)(src), \
                                   (__attribute__((address_space(3))) void*)(dst), 16, 0, 0)

  f32x4 acc[4][4];   // [nt codes][mt rows]
#pragma unroll
  for (int nt = 0; nt < 4; ++nt)
#pragma unroll
    for (int mt = 0; mt < 4; ++mt) acc[nt][mt] = (f32x4){0.f, 0.f, 0.f, 0.f};

#pragma unroll
  for (int kc = 0; kc < 16; ++kc) {
    const int k0 = kc * 32;
    __syncthreads();
    // ---- stage A (128 rows) + B (128 codes), hi+lo: 8 x 16B per thread ----
    GLD(pB0h + k0, &Bh[t * 8]);
    GLD(pB0l + k0, &Bl[t * 8]);
    GLD(pB1h + k0, &Bh[(256 + t) * 8]);
    GLD(pB1l + k0, &Bl[(256 + t) * 8]);
    GLD(pA0h + k0, &Ah[t * 8]);
    GLD(pA0l + k0, &Al[t * 8]);
    GLD(pA1h + k0, &Ah[(256 + t) * 8]);
    GLD(pA1l + k0, &Al[(256 + t) * 8]);
    __syncthreads();   // drains vmcnt (global_load_lds)
    // ---- fragments (swizzled read; LDS addresses loop-invariant) ----
    bf16x8 ch[4], cl[4];
#pragma unroll
    for (int nt = 0; nt < 4; ++nt) {
      const int o = (wc * 64 + nt * 16 + lm) * 32 + fcol;
      ch[nt] = *(bf16x8*)&Bh[o];
      cl[nt] = *(bf16x8*)&Bl[o];
    }
#pragma unroll
    for (int mt = 0; mt < 4; ++mt) {
      const int o = (wr * 64 + mt * 16 + lm) * 32 + fcol;
      const bf16x8 rh = *(bf16x8*)&Ah[o];
      const bf16x8 rl = *(bf16x8*)&Al[o];
      // swapped operands: D[code][row]; per-acc term order ch*rh, cl*rh, ch*rl (validated)
#pragma unroll
      for (int nt = 0; nt < 4; ++nt) {
        acc[nt][mt] = __builtin_amdgcn_mfma_f32_16x16x32_bf16(ch[nt], rh, acc[nt][mt], 0, 0, 0);
        acc[nt][mt] = __builtin_amdgcn_mfma_f32_16x16x32_bf16(cl[nt], rh, acc[nt][mt], 0, 0, 0);
        acc[nt][mt] = __builtin_amdgcn_mfma_f32_16x16x32_bf16(ch[nt], rl, acc[nt][mt], 0, 0, 0);
      }
    }
  }
#undef GLD

  // ---- epilogue: score = G - 0.5*||c||^2; codes in-lane (nt,r) + across lq ----
  float hc[4][4];
#pragma unroll
  for (int nt = 0; nt < 4; ++nt)
#pragma unroll
    for (int r = 0; r < 4; ++r)
      hc[nt][r] = 0.5f * Cn[c0 + wc * 64 + nt * 16 + lq * 4 + r];

#pragma unroll
  for (int mt = 0; mt < 4; ++mt) {   // wave-local row = mt*16 + lm
    float v1 = -3.4e38f, v2 = -3.4e38f, v3 = -3.4e38f;
    int   i1 = 0x7fffffff, i2 = 0x7fffffff;
#pragma unroll
    for (int nt = 0; nt < 4; ++nt)
#pragma unroll
      for (int r = 0; r < 4; ++r)
        top3_insert(acc[nt][mt][r] - hc[nt][r],
                    c0 + wc * 64 + nt * 16 + lq * 4 + r, v1, i1, v2, i2, v3);
#pragma unroll
    for (int off = 16; off <= 32; off <<= 1) {   // merge lanes lm, lm+16, lm+32, lm+48
      const float ov1 = __shfl_xor(v1, off); const int oi1 = __shfl_xor(i1, off);
      const float ov2 = __shfl_xor(v2, off); const int oi2 = __shfl_xor(i2, off);
      const float ov3 = __shfl_xor(v3, off);
      top3_insert(ov1, oi1, v1, i1, v2, i2, v3);
      top3_insert(ov2, oi2, v1, i1, v2, i2, v3);
      top3_insert(ov3, 0x7fffffff, v1, i1, v2, i2, v3);
    }
    if (lq == 0) mbuf[w][mt * 16 + lm] = make_float4(v1, pack_ii(i1, i2), v2, v3);
  }
  __syncthreads();
  if (t < 128) {   // row t: merge the 2 waves covering this row half
    const int half = t >> 6, rr = t & 63;
    float v1 = -3.4e38f, v2 = -3.4e38f, v3 = -3.4e38f;
    int   i1 = 0x7fffffff, i2 = 0x7fffffff;
#pragma unroll
    for (int ww = 0; ww < 2; ++ww) {
      float4 p = mbuf[half * 2 + ww][rr];
      const uint32_t bits = __float_as_uint(p.y);
      top3_insert(p.x, (int)(bits & 0xffffu), v1, i1, v2, i2, v3);
      top3_insert(p.z, (int)(bits >> 16),     v1, i1, v2, i2, v3);
      top3_insert(p.w, 0x7fffffff, v1, i1, v2, i2, v3);
    }
    partials[(size_t)ct * N_ROWS + m0 + t] = make_float4(v1, pack_ii(i1, i2), v2, v3);
  }
}

// ---- merge 16 code-tile partials per row -> idx + rescue mode (bit-packed) ----
// mode 2: gap >= EPS (identical to validated skip condition).
// mode 1: codes with mfma-score >= v1-EPS number <=4 AND no tile hides a 3rd
//         in-window entry (tile-v3 < window) -> candidate set provably complete.
//         Candidates encoded as (tile,slot) descriptors (5 bits each) in the word.
// mode 0: otherwise -> full np-exact scan (validated path).
__global__ __launch_bounds__(256)
void mergetop_kernel(const float4* __restrict__ partials, float* __restrict__ idx_out,
                     float* __restrict__ gap, int stage)
{
  const int row = blockIdx.x * 256 + threadIdx.x;
  float v1 = -3.4e38f, v2 = -3.4e38f, vm3 = -3.4e38f;
  int   i1 = 0x7fffffff, i2 = 0x7fffffff;
  float4 ptile[16];
#pragma unroll
  for (int ctt = 0; ctt < 16; ++ctt) {
    ptile[ctt] = partials[(size_t)ctt * N_ROWS + row];
    const uint32_t bits = __float_as_uint(ptile[ctt].y);
    top2_insert(ptile[ctt].x, (int)(bits & 0xffffu), v1, i1, v2, i2);
    top2_insert(ptile[ctt].z, (int)(bits >> 16),     v1, i1, v2, i2);
    vm3 = fmaxf(vm3, ptile[ctt].w);
  }
  idx_out[(size_t)row * NQ + stage] = (float)i1;
  if (v1 - v2 >= EPS_RESCUE) { gap[row] = __uint_as_float(2u); return; }
  const float window = v1 - EPS_RESCUE;
  uint32_t cnt = 0, descs = 0;
#pragma unroll
  for (int ctt = 0; ctt < 16; ++ctt) {
    if (ptile[ctt].x >= window) { if (cnt < 4) descs |= (uint32_t)(ctt * 2 + 0) << (5 * cnt); ++cnt; }
    if (ptile[ctt].z >= window) { if (cnt < 4) descs |= (uint32_t)(ctt * 2 + 1) << (5 * cnt); ++cnt; }
  }
  if (cnt > 4 || vm3 >= window) { gap[row] = __uint_as_float(0u); return; }
  gap[row] = __uint_as_float(1u | (cnt << 2) | (descs << 5));
}

// ---------------- np-fp32-mimic rescue: candidate mode (fast) or full scan ----------------
#define RESCUE_UNROLL 4

__global__ __launch_bounds__(256)
void rescue_kernel(const float* __restrict__ x, const float* __restrict__ cb,
                   const float* __restrict__ Cn, float* __restrict__ idxf,
                   const float* __restrict__ gap, const float4* __restrict__ partials,
                   int stage)
{
  const int row = blockIdx.x;
  const uint32_t g = __float_as_uint(gap[row]);
  const uint32_t mode = g & 3u;
  if (mode == 2u) return;
  const int t = threadIdx.x;
  const int lane = t & 63, w = t >> 6;
  __shared__ float rs[DIM];
  __shared__ float sd[4];
  __shared__ int   si[4];

  // every wave computes the identical residual f[8] (deterministic replay)
  float f[8];
  {
    const float* xp = x + (size_t)row * DIM + lane * 8;
    float4 a = *(const float4*)xp, b = *(const float4*)(xp + 4);
    f[0]=a.x; f[1]=a.y; f[2]=a.z; f[3]=a.w; f[4]=b.x; f[5]=b.y; f[6]=b.z; f[7]=b.w;
  }
  for (int p = 0; p < stage; ++p) {
    const int ip = (int)idxf[(size_t)row * NQ + p];
    const float* cp = cb + ((size_t)p * NCODES + ip) * DIM + lane * 8;
    float4 a = *(const float4*)cp, b = *(const float4*)(cp + 4);
    const float q[8] = {a.x, a.y, a.z, a.w, b.x, b.y, b.z, b.w};
#pragma unroll
    for (int k = 0; k < 8; ++k) {
      const float tt = __fsub_rn(q[k], f[k]);   // sg(xq - r)
      const float xr = __fadd_rn(f[k], tt);     // x_res (STE)
      f[k] = __fsub_rn(f[k], xr);               // next residual
    }
  }
  if (w == 0) {
#pragma unroll
    for (int k = 0; k < 8; ++k) rs[lane * 8 + k] = f[k];
  }
  __syncthreads();
  const float Rn = np_pairwise_sq512(rs, lane);

  const float* cbs = cb + (size_t)stage * NCODES * DIM;
  const float* Cns = Cn + stage * NCODES;

  if (mode == 1u) {          // candidate rescore: <=4 codes, np-exact arithmetic
    if (w == 0) {
      const int cnt = (int)((g >> 2) & 7u);
      float dbest = 3.4e38f;
      int   ibest = 0x7fffffff;
      for (int u = 0; u < cnt; ++u) {
        const uint32_t d5 = (g >> (5 + 5 * u)) & 31u;
        const float4 p = partials[(size_t)(d5 >> 1) * N_ROWS + row];
        const uint32_t bits = __float_as_uint(p.y);
        const int c = (int)((d5 & 1u) ? (bits >> 16) : (bits & 0xffffu));
        const float* cp = cbs + (size_t)c * DIM + lane * 8;
        float4 a = *(const float4*)cp, b = *(const float4*)(cp + 4);
        double s = (double)f[0] * a.x + (double)f[1] * a.y + (double)f[2] * a.z + (double)f[3] * a.w
                 + (double)f[4] * b.x + (double)f[5] * b.y + (double)f[6] * b.z + (double)f[7] * b.w;
#pragma unroll
        for (int off = 32; off; off >>= 1) s += __shfl_xor(s, off);
        const float G = (float)s;
        const float d = __fsub_rn(__fadd_rn(Rn, Cns[c]), __fmul_rn(2.0f, G));
        if (d < dbest || (d == dbest && c < ibest)) { dbest = d; ibest = c; }
      }
      if (lane == 0) idxf[(size_t)row * NQ + stage] = (float)ibest;
    }
    return;
  }

  // ---- mode 0: full scan (validated 4-wave path) ----
  float dbest = 3.4e38f;
  int   ibest = 0x7fffffff;
  const int cbeg = w * (NCODES / 4);
  for (int cc = cbeg; cc < cbeg + NCODES / 4; cc += RESCUE_UNROLL) {
    float4 a[RESCUE_UNROLL], b[RESCUE_UNROLL];
#pragma unroll
    for (int u = 0; u < RESCUE_UNROLL; ++u) {
      const float* cp = cbs + (size_t)(cc + u) * DIM + lane * 8;
      a[u] = *(const float4*)cp;
      b[u] = *(const float4*)(cp + 4);
    }
    double s[RESCUE_UNROLL];
#pragma unroll
    for (int u = 0; u < RESCUE_UNROLL; ++u) {
      s[u] = (double)f[0] * a[u].x + (double)f[1] * a[u].y + (double)f[2] * a[u].z + (double)f[3] * a[u].w
           + (double)f[4] * b[u].x + (double)f[5] * b[u].y + (double)f[6] * b[u].z + (double)f[7] * b[u].w;
    }
#pragma unroll
    for (int off = 32; off; off >>= 1) {
#pragma unroll
      for (int u = 0; u < RESCUE_UNROLL; ++u) s[u] += __shfl_xor(s[u], off);
    }
#pragma unroll
    for (int u = 0; u < RESCUE_UNROLL; ++u) {
      const float G = (float)s[u];
      const float d = __fsub_rn(__fadd_rn(Rn, Cns[cc + u]), __fmul_rn(2.0f, G));
      if (d < dbest || (d == dbest && (cc + u) < ibest)) { dbest = d; ibest = cc + u; }
    }
  }
  if (lane == 0) { sd[w] = dbest; si[w] = ibest; }
  __syncthreads();
  if (t == 0) {
    float db = sd[0]; int ib = si[0];
#pragma unroll
    for (int ww = 1; ww < 4; ++ww) {
      if (sd[ww] < db || (sd[ww] == db && si[ww] < ib)) { db = sd[ww]; ib = si[ww]; }
    }
    idxf[(size_t)row * NQ + stage] = (float)ib;
  }
}

// ---------------- gather chosen code, accumulate x_q, loss, next-stage residual ----------------
__global__ __launch_bounds__(128)
void update_kernel(const float* __restrict__ x, float* __restrict__ xq_acc,
                   const float* __restrict__ cb, const float* __restrict__ idxf,
                   double* __restrict__ loss_arr,
                   ushort* __restrict__ resh, ushort* __restrict__ resl, int stage)
{
  const int n = blockIdx.x;
  const int t = threadIdx.x;
  const int idx = (int)idxf[(size_t)n * NQ + stage];
  const size_t g = (size_t)n * DIM + t * 4;

  float4 cv = *(const float4*)(cb + (size_t)idx * DIM + t * 4);
  float4 av;
  if (stage) av = *(const float4*)(xq_acc + g);
  else { av.x = 0.f; av.y = 0.f; av.z = 0.f; av.w = 0.f; }
  av.x += cv.x; av.y += cv.y; av.z += cv.z; av.w += cv.w;
  *(float4*)(xq_acc + g) = av;

  float4 xv = *(const float4*)(x + g);
  const float rx = xv.x - av.x, ry = xv.y - av.y, rz = xv.z - av.z, rw = xv.w - av.w;

  // next-stage residual bf16 hi/lo split (identical formula to cbsplit on x - xq_acc)
  {
    ushort4 h, l;
    h.x = f2bf(rx); l.x = f2bf(rx - bf2f(h.x));
    h.y = f2bf(ry); l.y = f2bf(ry - bf2f(h.y));
    h.z = f2bf(rz); l.z = f2bf(rz - bf2f(h.z));
    h.w = f2bf(rw); l.w = f2bf(rw - bf2f(h.w));
    *(ushort4*)(resh + g) = h;
    *(ushort4*)(resl + g) = l;
  }

  float s = rx * rx + ry * ry + rz * rz + rw * rw;
#pragma unroll
  for (int off = 32; off; off >>= 1) s += __shfl_down(s, off);
  __shared__ float wsum[2];
  if ((t & 63) == 0) wsum[t >> 6] = s;
  __syncthreads();
  if (t == 0) atomicAdd(&loss_arr[n & 511], (double)(wsum[0] + wsum[1]));  // 512-way fan-out
}

__global__ __launch_bounds__(64)
void finalize_kernel(const double* __restrict__ loss_arr, float* __restrict__ out_loss) {
  double s = 0.0;
  for (int i = threadIdx.x; i < 512; i += 64) s += loss_arr[i];
#pragma unroll
  for (int off = 32; off; off >>= 1) s += __shfl_down(s, off);
  if (threadIdx.x == 0)
    *out_loss = (float)(((1.0 + BETA) / ((double)NQ * (double)N_ROWS * (double)DIM)) * s);
}

extern "C" void kernel_launch(void* const* d_in, const int* in_sizes, int n_in,
                              void* d_out, int out_size, void* d_ws, size_t ws_size,
                              hipStream_t stream) {
  const float* x  = (const float*)d_in[0];
  const float* cb = (const float*)d_in[1];

  float* out_xq   = (float*)d_out;                       // [N, D]
  float* out_loss = out_xq + (size_t)N_ROWS * DIM;       // scalar
  float* out_idx  = out_loss + 1;                        // [N, Q] as float

  char* ws = (char*)d_ws;
  double* loss_arr = (double*)(ws + WS_LOSS);
  float*  Cn       = (float*) (ws + WS_CN);
  float*  gap      = (float*) (ws + WS_GAP);
  float4* partials = (float4*)(ws + WS_PART);
  ushort* cb_hi    = (ushort*)(ws + WS_CBH);
  ushort* cb_lo    = (ushort*)(ws + WS_CBL);
  ushort* res_hi   = (ushort*)(ws + WS_RESH);
  ushort* res_lo   = (ushort*)(ws + WS_RESL);

  hipMemsetAsync(ws + WS_LOSS, 0, 4096, stream);
  cbsplit_kernel<<<(NQ * NCODES * DIM) / 2048, 256, 0, stream>>>(cb, cb_hi, cb_lo);
  cbsplit_kernel<<<((size_t)N_ROWS * DIM) / 2048, 256, 0, stream>>>(x, res_hi, res_lo);  // stage-0 residual = x
  cnorm_kernel<<<NQ * NCODES, 64, 0, stream>>>(cb, Cn);

  for (int q = 0; q < NQ; ++q) {
    const float* cbq = cb + (size_t)q * NCODES * DIM;
    argmax_kernel<<<256 * 16, 256, 0, stream>>>(res_hi, res_lo,
                                                cb_hi + (size_t)q * NCODES * DIM,
                                                cb_lo + (size_t)q * NCODES * DIM,
                                                Cn + q * NCODES, partials);
    mergetop_kernel<<<N_ROWS / 256, 256, 0, stream>>>(partials, out_idx, gap, q);
    rescue_kernel<<<N_ROWS, 256, 0, stream>>>(x, cb, Cn, out_idx, gap, partials, q);
    update_kernel<<<N_ROWS, 128, 0, stream>>>(x, out_xq, cbq, out_idx, loss_arr, res_hi, res_lo, q);
  }
  finalize_kernel<<<1, 64, 0, stream>>>(loss_arr, out_loss);
}